// Round 2
// baseline (3352.864 us; speedup 1.0000x reference)
//
#include <hip/hip_runtime.h>
#include <math.h>

#define B_ 32
#define C_ 256
#define H_ 28
#define W_ 28
#define NPIX 784
#define HK 14
#define NKPIX 196
#define CM 1024
#define EPS_ 1e-5f
#define LN_INVN (1.0f / (C_ * NPIX))

__device__ __forceinline__ float gelu_f(float x) {
    return 0.5f * x * (1.0f + erff(x * 0.70710678118654752f));
}

__global__ void zero_kernel(float* p) { p[threadIdx.x] = 0.f; }

// ---------------- LPU: depthwise 3x3 + bias + residual, fused LN1 stats ----------------
__global__ void lpu_kernel(const float* __restrict__ x, const float* __restrict__ w,
                           const float* __restrict__ bias, float* __restrict__ out,
                           float* __restrict__ stats) {
    int idx = blockIdx.x * blockDim.x + threadIdx.x;
    int p = idx % NPIX;
    int c = (idx / NPIX) % C_;
    int b = idx / (NPIX * C_);
    int y = p / W_, xx = p % W_;
    const float* xb = x + ((size_t)b * C_ + c) * NPIX;
    const float* wc = w + c * 9;
    float acc = bias[c] + x[idx];
    #pragma unroll
    for (int dy = -1; dy <= 1; ++dy) {
        int yy = y + dy;
        if (yy < 0 || yy >= H_) continue;
        #pragma unroll
        for (int dx = -1; dx <= 1; ++dx) {
            int xc = xx + dx;
            if (xc < 0 || xc >= W_) continue;
            acc += wc[(dy + 1) * 3 + (dx + 1)] * xb[yy * W_ + xc];
        }
    }
    out[idx] = acc;
    // block-level LN stats reduction (block is within one b: 200704 % 256 == 0)
    float s = acc, s2 = acc * acc;
    #pragma unroll
    for (int o = 32; o > 0; o >>= 1) {
        s += __shfl_down(s, o);
        s2 += __shfl_down(s2, o);
    }
    __shared__ float ss[4][2];
    int wv = threadIdx.x >> 6;
    if ((threadIdx.x & 63) == 0) { ss[wv][0] = s; ss[wv][1] = s2; }
    __syncthreads();
    if (threadIdx.x == 0) {
        float S = ss[0][0] + ss[1][0] + ss[2][0] + ss[3][0];
        float S2 = ss[0][1] + ss[1][1] + ss[2][1] + ss[3][1];
        atomicAdd(&stats[b * 2], S);
        atomicAdd(&stats[b * 2 + 1], S2);
    }
}

// ---------------- kv depthwise 2x2 stride-2 conv (on pre-LN x1) ----------------
__global__ void kvconv_kernel(const float* __restrict__ x, const float* __restrict__ w,
                              const float* __restrict__ bias, float* __restrict__ out) {
    int idx = blockIdx.x * blockDim.x + threadIdx.x;
    if (idx >= B_ * C_ * NKPIX) return;
    int p = idx % NKPIX;
    int c = (idx / NKPIX) % C_;
    int b = idx / (NKPIX * C_);
    int yo = p / HK, xo = p % HK;
    const float* xb = x + ((size_t)b * C_ + c) * NPIX;
    const float* wc = w + c * 4;
    float acc = bias[c];
    #pragma unroll
    for (int dy = 0; dy < 2; ++dy)
        #pragma unroll
        for (int dx = 0; dx < 2; ++dx)
            acc += wc[dy * 2 + dx] * xb[(2 * yo + dy) * W_ + (2 * xo + dx)];
    out[idx] = acc;
}

// ---------------- tiled GEMM: out[b][m][n] = sum_k A[m][k] * B[b][k][n] ----------------
// EPI 0: +bias, store [b][m][N].  EPI 1: +bias,BN,GELU, store [b][m][N].
// EPI 2: +bias, flat store b*strideO + n*256 + m with flat residual (+LN stats).
// LNB: apply per-sample LayerNorm (from lnst sums) to B elements on load.
template <int EPI, bool LNB, bool STATS>
__global__ __launch_bounds__(256) void gemm_kernel(
    const float* __restrict__ A, const float* __restrict__ Bbase, long strideB,
    int K, int ldb, int N,
    const float* __restrict__ lnst,
    const float* __restrict__ bias,
    const float* __restrict__ bng, const float* __restrict__ bnb,
    const float* __restrict__ bnm, const float* __restrict__ bnv,
    const float* __restrict__ res, float* __restrict__ out, long strideO,
    float* __restrict__ ostats) {
    __shared__ float As[16][132];
    __shared__ float Bs[16][64];
    const int t = threadIdx.x;
    const int tx = t & 15, ty = t >> 4;
    const int n0 = blockIdx.x * 64;
    const int m0 = blockIdx.y * 128;
    const int b = blockIdx.z;
    const float* Bp = Bbase + (long)b * strideB;
    float lm = 0.f, lr = 1.f;
    if (LNB) {
        float s = lnst[b * 2], s2 = lnst[b * 2 + 1];
        lm = s * LN_INVN;
        lr = rsqrtf(s2 * LN_INVN - lm * lm + EPS_);
    }
    float acc[8][4];
    #pragma unroll
    for (int r = 0; r < 8; ++r)
        #pragma unroll
        for (int c = 0; c < 4; ++c) acc[r][c] = 0.f;

    for (int k0 = 0; k0 < K; k0 += 16) {
        __syncthreads();
        #pragma unroll
        for (int i = 0; i < 2; ++i) {
            int f = t + i * 256;
            int m = f >> 2, k4 = (f & 3) << 2;
            float4 av = *(const float4*)(A + (long)(m0 + m) * K + k0 + k4);
            As[k4 + 0][m] = av.x;
            As[k4 + 1][m] = av.y;
            As[k4 + 2][m] = av.z;
            As[k4 + 3][m] = av.w;
        }
        {
            int kk = t >> 4, n4 = (t & 15) << 2;
            float4 bv = make_float4(0.f, 0.f, 0.f, 0.f);
            if (n0 + n4 < N) {
                bv = *(const float4*)(Bp + (long)(k0 + kk) * ldb + n0 + n4);
                if (LNB) {
                    bv.x = (bv.x - lm) * lr;
                    bv.y = (bv.y - lm) * lr;
                    bv.z = (bv.z - lm) * lr;
                    bv.w = (bv.w - lm) * lr;
                }
            }
            *(float4*)&Bs[kk][n4] = bv;
        }
        __syncthreads();
        #pragma unroll
        for (int kk = 0; kk < 16; ++kk) {
            float4 a0 = *(const float4*)&As[kk][ty * 8];
            float4 a1 = *(const float4*)&As[kk][ty * 8 + 4];
            float4 b0 = *(const float4*)&Bs[kk][tx * 4];
            float am[8] = {a0.x, a0.y, a0.z, a0.w, a1.x, a1.y, a1.z, a1.w};
            float bm[4] = {b0.x, b0.y, b0.z, b0.w};
            #pragma unroll
            for (int r = 0; r < 8; ++r)
                #pragma unroll
                for (int c = 0; c < 4; ++c)
                    acc[r][c] += am[r] * bm[c];
        }
    }

    int n = n0 + tx * 4;
    float s = 0.f, s2 = 0.f;
    if (EPI == 0 || EPI == 1) {
        if (n < N) {
            #pragma unroll
            for (int r = 0; r < 8; ++r) {
                int m = m0 + ty * 8 + r;
                float cb = bias[m];
                float4 y;
                if (EPI == 1) {
                    float sc = bng[m] * rsqrtf(bnv[m] + EPS_);
                    float sh = bnb[m] - bnm[m] * sc;
                    y.x = gelu_f((acc[r][0] + cb) * sc + sh);
                    y.y = gelu_f((acc[r][1] + cb) * sc + sh);
                    y.z = gelu_f((acc[r][2] + cb) * sc + sh);
                    y.w = gelu_f((acc[r][3] + cb) * sc + sh);
                } else {
                    y.x = acc[r][0] + cb;
                    y.y = acc[r][1] + cb;
                    y.z = acc[r][2] + cb;
                    y.w = acc[r][3] + cb;
                }
                *(float4*)(out + (long)b * strideO + (long)m * N + n) = y;
            }
        }
    } else {
        // wo: y is [p][oc] row-major flat; residual is x1's flat view (raw reinterpret)
        #pragma unroll
        for (int r = 0; r < 8; ++r) {
            int m = m0 + ty * 8 + r;
            float cb = bias[m];
            #pragma unroll
            for (int c = 0; c < 4; ++c) {
                if (n + c < N) {
                    long j = (long)b * strideO + (long)(n + c) * 256 + m;
                    float yv = acc[r][c] + cb + res[j];
                    out[j] = yv;
                    if (STATS) { s += yv; s2 += yv * yv; }
                }
            }
        }
    }
    if (STATS) {
        #pragma unroll
        for (int o = 32; o > 0; o >>= 1) {
            s += __shfl_down(s, o);
            s2 += __shfl_down(s2, o);
        }
        if ((t & 63) == 0) {
            atomicAdd(&ostats[b * 2], s);
            atomicAdd(&ostats[b * 2 + 1], s2);
        }
    }
}

// ---------------- attention: online softmax, channel-major layouts ----------------
// q: [b,256,784], k/v: [b,256,196], pos_b: [8,784,196], out tmp: [b,256,784]
__global__ void attn_kernel(const float* __restrict__ q, const float* __restrict__ k,
                            const float* __restrict__ v, const float* __restrict__ pos_b,
                            float* __restrict__ out) {
    int qb4 = blockIdx.x & 3;
    int h = (blockIdx.x >> 2) & 7;
    int b = blockIdx.x >> 5;
    __shared__ float ks[32 * NKPIX];
    __shared__ float vs[32 * NKPIX];
    const float* kbp = k + ((long)b * 256 + h * 32) * NKPIX;
    const float* vbp = v + ((long)b * 256 + h * 32) * NKPIX;
    for (int i = threadIdx.x; i < 32 * NKPIX; i += 256) {
        ks[i] = kbp[i];
        vs[i] = vbp[i];
    }
    __syncthreads();
    if (threadIdx.x >= 196) return;
    int iq = qb4 * 196 + threadIdx.x;
    float qr[32];
    const float* qp = q + ((long)b * 256 + h * 32) * NPIX + iq;
    #pragma unroll
    for (int d = 0; d < 32; ++d) qr[d] = qp[d * NPIX];
    const float* pb = pos_b + ((long)h * NPIX + iq) * NKPIX;
    float m = -1e30f, l = 0.f;
    float o[32];
    #pragma unroll
    for (int d = 0; d < 32; ++d) o[d] = 0.f;
    const float scale = 0.17677669529663689f;  // 1/sqrt(32)
    for (int j = 0; j < NKPIX; ++j) {
        float sdot = 0.f;
        #pragma unroll
        for (int d = 0; d < 32; ++d) sdot += qr[d] * ks[d * NKPIX + j];
        sdot = sdot * scale + pb[j];
        float nm = fmaxf(m, sdot);
        float alpha = __expf(m - nm);
        float pexp = __expf(sdot - nm);
        l = l * alpha + pexp;
        #pragma unroll
        for (int d = 0; d < 32; ++d) o[d] = o[d] * alpha + pexp * vs[d * NKPIX + j];
        m = nm;
    }
    float inv = 1.f / l;
    float* op = out + ((long)b * 256 + h * 32) * NPIX + iq;
    #pragma unroll
    for (int d = 0; d < 32; ++d) op[d * NPIX] = o[d] * inv;
}

// ---------------- conv2 GEMM with on-the-fly B = gelu(bn2(dwconv3x3(t2))) ----------------
__global__ __launch_bounds__(256) void conv2_kernel(
    const float* __restrict__ W2, const float* __restrict__ t2,
    const float* __restrict__ dww, const float* __restrict__ dwb,
    const float* __restrict__ g2, const float* __restrict__ b2,
    const float* __restrict__ m2, const float* __restrict__ v2,
    const float* __restrict__ c2b,
    const float* __restrict__ g3, const float* __restrict__ b3,
    const float* __restrict__ m3, const float* __restrict__ v3,
    const float* __restrict__ x2, float* __restrict__ out) {
    __shared__ float As[16][132];
    __shared__ float Bs[16][64];
    const int t = threadIdx.x;
    const int tx = t & 15, ty = t >> 4;
    const int n0 = blockIdx.x * 64;
    const int m0 = blockIdx.y * 128;
    const int b = blockIdx.z;
    float acc[8][4];
    #pragma unroll
    for (int r = 0; r < 8; ++r)
        #pragma unroll
        for (int c = 0; c < 4; ++c) acc[r][c] = 0.f;

    for (int k0 = 0; k0 < CM; k0 += 16) {
        __syncthreads();
        #pragma unroll
        for (int i = 0; i < 2; ++i) {
            int f = t + i * 256;
            int m = f >> 2, k4 = (f & 3) << 2;
            float4 av = *(const float4*)(W2 + (long)(m0 + m) * CM + k0 + k4);
            As[k4 + 0][m] = av.x;
            As[k4 + 1][m] = av.y;
            As[k4 + 2][m] = av.z;
            As[k4 + 3][m] = av.w;
        }
        #pragma unroll
        for (int r2 = 0; r2 < 4; ++r2) {
            int e = r2 * 256 + t;
            int kk = e >> 6, nn = e & 63;
            int p = n0 + nn;
            float val = 0.f;
            if (p < NPIX) {
                int cm = k0 + kk;
                int py = p / W_, px = p % W_;
                const float* tb = t2 + ((long)b * CM + cm) * NPIX;
                const float* wc = dww + cm * 9;
                float a = dwb[cm];
                #pragma unroll
                for (int dy = -1; dy <= 1; ++dy) {
                    int yy = py + dy;
                    if (yy < 0 || yy >= H_) continue;
                    #pragma unroll
                    for (int dx = -1; dx <= 1; ++dx) {
                        int xc = px + dx;
                        if (xc < 0 || xc >= W_) continue;
                        a += wc[(dy + 1) * 3 + (dx + 1)] * tb[yy * W_ + xc];
                    }
                }
                float sc = g2[cm] * rsqrtf(v2[cm] + EPS_);
                val = gelu_f(a * sc + (b2[cm] - m2[cm] * sc));
            }
            Bs[kk][nn] = val;
        }
        __syncthreads();
        #pragma unroll
        for (int kk = 0; kk < 16; ++kk) {
            float4 a0 = *(const float4*)&As[kk][ty * 8];
            float4 a1 = *(const float4*)&As[kk][ty * 8 + 4];
            float4 b0 = *(const float4*)&Bs[kk][tx * 4];
            float am[8] = {a0.x, a0.y, a0.z, a0.w, a1.x, a1.y, a1.z, a1.w};
            float bm[4] = {b0.x, b0.y, b0.z, b0.w};
            #pragma unroll
            for (int r = 0; r < 8; ++r)
                #pragma unroll
                for (int c = 0; c < 4; ++c)
                    acc[r][c] += am[r] * bm[c];
        }
    }

    int n = n0 + tx * 4;
    if (n < NPIX) {
        #pragma unroll
        for (int r = 0; r < 8; ++r) {
            int m = m0 + ty * 8 + r;
            float sc = g3[m] * rsqrtf(v3[m] + EPS_);
            float sh = b3[m] - m3[m] * sc;
            float cb = c2b[m];
            long base = ((long)b * C_ + m) * NPIX + n;
            float4 rv = *(const float4*)(x2 + base);
            float4 y;
            y.x = rv.x + (acc[r][0] + cb) * sc + sh;
            y.y = rv.y + (acc[r][1] + cb) * sc + sh;
            y.z = rv.z + (acc[r][2] + cb) * sc + sh;
            y.w = rv.w + (acc[r][3] + cb) * sc + sh;
            *(float4*)(out + base) = y;
        }
    }
}

extern "C" void kernel_launch(void* const* d_in, const int* in_sizes, int n_in,
                              void* d_out, int out_size, void* d_ws, size_t ws_size,
                              hipStream_t stream) {
    const float* x     = (const float*)d_in[0];
    const float* lpu_w = (const float*)d_in[1];
    const float* lpu_b = (const float*)d_in[2];
    const float* dw_w  = (const float*)d_in[3];
    const float* dw_b  = (const float*)d_in[4];
    const float* wq    = (const float*)d_in[5];
    const float* bq    = (const float*)d_in[6];
    const float* wk    = (const float*)d_in[7];
    const float* bk    = (const float*)d_in[8];
    const float* wv    = (const float*)d_in[9];
    const float* bv    = (const float*)d_in[10];
    const float* wo    = (const float*)d_in[11];
    const float* bo    = (const float*)d_in[12];
    const float* posb  = (const float*)d_in[13];
    const float* c1_w  = (const float*)d_in[14];
    const float* c1_b  = (const float*)d_in[15];
    const float* bn1_g = (const float*)d_in[16];
    const float* bn1_b = (const float*)d_in[17];
    const float* bn1_m = (const float*)d_in[18];
    const float* bn1_v = (const float*)d_in[19];
    const float* dw2_w = (const float*)d_in[20];
    const float* dw2_b = (const float*)d_in[21];
    const float* bn2_g = (const float*)d_in[22];
    const float* bn2_b = (const float*)d_in[23];
    const float* bn2_m = (const float*)d_in[24];
    const float* bn2_v = (const float*)d_in[25];
    const float* c2_w  = (const float*)d_in[26];
    const float* c2_b  = (const float*)d_in[27];
    const float* bn3_g = (const float*)d_in[28];
    const float* bn3_b = (const float*)d_in[29];
    const float* bn3_m = (const float*)d_in[30];
    const float* bn3_v = (const float*)d_in[31];

    float* ws = (float*)d_ws;
    const long n1  = (long)B_ * C_ * NPIX;    // 6,422,528
    const long nkv = (long)B_ * C_ * NKPIX;   // 1,605,632
    const long nm  = (long)B_ * CM * NPIX;    // 25,690,112

    float* x1  = ws;               // LPU out (later: residual source for wo)
    float* xn  = ws + n1;          // attn tmp
    float* qb  = ws + 2 * n1;      // q [b,256,784]; reused as x2 after attn
    float* kvb = ws + 3 * n1;
    float* kb  = kvb + nkv;
    float* vb  = kb + nkv;
    float* t2  = ws + 3 * n1 + 3 * nkv;
    float* stats = t2 + nm;        // [0..63]: ln1 (sum,sumsq per b); [64..127]: ln2
    float* tmp = xn;
    float* x2  = qb;
    float* outp = (float*)d_out;

    const long sO1 = (long)C_ * NPIX;   // 200704
    const long sOk = (long)C_ * NKPIX;  // 50176
    const long sT2 = (long)CM * NPIX;   // 802816

    zero_kernel<<<1, 128, 0, stream>>>(stats);
    lpu_kernel<<<(int)(n1 / 256), 256, 0, stream>>>(x, lpu_w, lpu_b, x1, stats);
    kvconv_kernel<<<(int)((nkv + 255) / 256), 256, 0, stream>>>(x1, dw_w, dw_b, kvb);
    // q = wq @ LN(x1):  [b,256,784]
    gemm_kernel<0, true, false><<<dim3(13, 2, B_), 256, 0, stream>>>(
        wq, x1, sO1, C_, NPIX, NPIX, stats, bq,
        nullptr, nullptr, nullptr, nullptr, nullptr, qb, sO1, nullptr);
    // k,v = wk/wv @ kv:  [b,256,196]
    gemm_kernel<0, false, false><<<dim3(4, 2, B_), 256, 0, stream>>>(
        wk, kvb, sOk, C_, NKPIX, NKPIX, nullptr, bk,
        nullptr, nullptr, nullptr, nullptr, nullptr, kb, sOk, nullptr);
    gemm_kernel<0, false, false><<<dim3(4, 2, B_), 256, 0, stream>>>(
        wv, kvb, sOk, C_, NKPIX, NKPIX, nullptr, bv,
        nullptr, nullptr, nullptr, nullptr, nullptr, vb, sOk, nullptr);
    attn_kernel<<<B_ * 32, 256, 0, stream>>>(qb, kb, vb, posb, tmp);
    // x2 = flat(tmp @ wo.T + bo) + flat(x1), with fused LN2 stats
    gemm_kernel<2, false, true><<<dim3(13, 2, B_), 256, 0, stream>>>(
        wo, tmp, sO1, C_, NPIX, NPIX, nullptr, bo,
        nullptr, nullptr, nullptr, nullptr, x1, x2, sO1, stats + 64);
    // t2 = gelu(bn1(c1_w @ LN(x2)))
    gemm_kernel<1, true, false><<<dim3(13, 8, B_), 256, 0, stream>>>(
        c1_w, x2, sO1, C_, NPIX, NPIX, stats + 64, c1_b,
        bn1_g, bn1_b, bn1_m, bn1_v, nullptr, t2, sT2, nullptr);
    // out = x2 + bn3(c2_w @ gelu(bn2(dwconv(t2))))
    conv2_kernel<<<dim3(13, 2, B_), 256, 0, stream>>>(
        c2_w, t2, dw2_w, dw2_b, bn2_g, bn2_b, bn2_m, bn2_v,
        c2_b, bn3_g, bn3_b, bn3_m, bn3_v, x2, outp);
}

// Round 3
// 1138.456 us; speedup vs baseline: 2.9451x; 2.9451x over previous
//
#include <hip/hip_runtime.h>
#include <math.h>

#define B_ 32
#define C_ 256
#define H_ 28
#define W_ 28
#define NPIX 784
#define HK 14
#define NKPIX 196
#define CM 1024
#define EPS_ 1e-5f
#define LN_INVN (1.0f / (C_ * NPIX))

typedef __attribute__((ext_vector_type(8))) short short8;
typedef __attribute__((ext_vector_type(4))) float float4_;

__device__ __forceinline__ float gelu_f(float x) {
    return 0.5f * x * (1.0f + erff(x * 0.70710678118654752f));
}
__device__ __forceinline__ short f2bf(float f) {
    union { float f; unsigned u; } x; x.f = f;
    unsigned r = x.u + 0x7FFF + ((x.u >> 16) & 1);
    return (short)(r >> 16);
}
__device__ __forceinline__ float bf2f(short s) {
    union { unsigned u; float f; } x; x.u = ((unsigned)(unsigned short)s) << 16;
    return x.f;
}

__global__ void zero_kernel(float* p) { p[threadIdx.x] = 0.f; }

// ---- convert all 6 weight matrices to bf16 (layout [oc][k], k contiguous) ----
__global__ void wconv_kernel(const float* __restrict__ wq, const float* __restrict__ wk,
                             const float* __restrict__ wv, const float* __restrict__ wo,
                             const float* __restrict__ c1, const float* __restrict__ c2,
                             short* __restrict__ dst) {
    int idx = blockIdx.x * 256 + threadIdx.x;  // total 786432
    const float* src; int off;
    if (idx < 65536)       { src = wq; off = idx; }
    else if (idx < 131072) { src = wk; off = idx - 65536; }
    else if (idx < 196608) { src = wv; off = idx - 131072; }
    else if (idx < 262144) { src = wo; off = idx - 196608; }
    else if (idx < 524288) { src = c1; off = idx - 262144; }
    else                   { src = c2; off = idx - 524288; }
    dst[idx] = f2bf(src[off]);
}

// ---- LPU: depthwise 3x3 + bias + residual (fp32 channel-major) + LN1 stats ----
__global__ void lpu_kernel(const float* __restrict__ x, const float* __restrict__ w,
                           const float* __restrict__ bias, float* __restrict__ out,
                           float* __restrict__ stats) {
    int idx = blockIdx.x * blockDim.x + threadIdx.x;
    int p = idx % NPIX;
    int c = (idx / NPIX) % C_;
    int b = idx / (NPIX * C_);
    int y = p / W_, xx = p % W_;
    const float* xb = x + ((size_t)b * C_ + c) * NPIX;
    const float* wc = w + c * 9;
    float acc = bias[c] + x[idx];
    #pragma unroll
    for (int dy = -1; dy <= 1; ++dy) {
        int yy = y + dy;
        if (yy < 0 || yy >= H_) continue;
        #pragma unroll
        for (int dx = -1; dx <= 1; ++dx) {
            int xc = xx + dx;
            if (xc < 0 || xc >= W_) continue;
            acc += wc[(dy + 1) * 3 + (dx + 1)] * xb[yy * W_ + xc];
        }
    }
    out[idx] = acc;
    float s = acc, s2 = acc * acc;
    #pragma unroll
    for (int o = 32; o > 0; o >>= 1) {
        s += __shfl_down(s, o);
        s2 += __shfl_down(s2, o);
    }
    __shared__ float ss[4][2];
    int wv = threadIdx.x >> 6;
    if ((threadIdx.x & 63) == 0) { ss[wv][0] = s; ss[wv][1] = s2; }
    __syncthreads();
    if (threadIdx.x == 0) {
        atomicAdd(&stats[b * 2], ss[0][0] + ss[1][0] + ss[2][0] + ss[3][0]);
        atomicAdd(&stats[b * 2 + 1], ss[0][1] + ss[1][1] + ss[2][1] + ss[3][1]);
    }
}

// ---- transpose + LayerNorm: fp32 [b][256][784] -> bf16 [b][784][256] ----
__global__ void tln_kernel(const float* __restrict__ X, const float* __restrict__ st,
                           short* __restrict__ Y) {
    __shared__ float tile[32][33];
    int p0 = blockIdx.x * 32, c0 = blockIdx.y * 32, b = blockIdx.z;
    int tr = threadIdx.x >> 5, tc = threadIdx.x & 31;
    #pragma unroll
    for (int r = 0; r < 4; ++r) {
        int c = c0 + tr + r * 8, p = p0 + tc;
        tile[tr + r * 8][tc] = (p < NPIX) ? X[((long)b * C_ + c) * NPIX + p] : 0.f;
    }
    float sm = st[b * 2] * LN_INVN;
    float lr = rsqrtf(st[b * 2 + 1] * LN_INVN - sm * sm + EPS_);
    __syncthreads();
    #pragma unroll
    for (int r = 0; r < 4; ++r) {
        int p = p0 + tr + r * 8, c = c0 + tc;
        if (p < NPIX) Y[((long)b * NPIX + p) * C_ + c] = f2bf((tile[tc][tr + r * 8] - sm) * lr);
    }
}

// ---- kv depthwise 2x2 stride-2 (x1 fp32 channel-major -> bf16 pixel-major) ----
__global__ void kvconv_kernel(const float* __restrict__ x1, const float* __restrict__ w,
                              const float* __restrict__ bias, short* __restrict__ out) {
    int idx = blockIdx.x * 256 + threadIdx.x;
    if (idx >= B_ * NKPIX * C_) return;
    int c = idx & 255;
    int rest = idx >> 8;
    int p = rest % NKPIX;
    int b = rest / NKPIX;
    int yo = p / HK, xo = p % HK;
    const float* xb = x1 + ((long)b * C_ + c) * NPIX;
    const float* wc = w + c * 4;
    float a = bias[c]
            + wc[0] * xb[(2 * yo) * W_ + 2 * xo]     + wc[1] * xb[(2 * yo) * W_ + 2 * xo + 1]
            + wc[2] * xb[(2 * yo + 1) * W_ + 2 * xo] + wc[3] * xb[(2 * yo + 1) * W_ + 2 * xo + 1];
    out[idx] = f2bf(a);
}

// ---- MFMA GEMM: D[b][p][oc] = sum_k Act[b][p][k] * Wb[oc][k]  (bf16 in, fp32 acc) ----
// EPI 0: +bias -> bf16 out[b][p][oc]
// EPI 1: +bias, BN, GELU -> bf16 out[b][p][oc]
// EPI 2: +bias + res[flat p*256+oc] -> fp32 out same flat order, + LN stats
// EPI 3: +bias, BN, + res (channel-major) -> fp32 out channel-major [b][oc][p]
template <int EPI>
__global__ __launch_bounds__(256) void mfma_gemm(
    const short* __restrict__ Act, const short* __restrict__ Wb,
    int M, int N, int K,
    const float* __restrict__ bias,
    const float* __restrict__ g, const float* __restrict__ bb,
    const float* __restrict__ mm, const float* __restrict__ vv,
    const float* __restrict__ res, float* __restrict__ ostats,
    short* __restrict__ outh, float* __restrict__ outf) {
    __shared__ short As[128 * 40];
    __shared__ short Bs[128 * 40];
    const int t = threadIdx.x;
    const int m0 = blockIdx.x * 128;
    const int n0 = blockIdx.y * 128;
    const int b = blockIdx.z;
    const int w = t >> 6, lane = t & 63;
    const int wm = (w & 1) * 64, wn = (w >> 1) * 64;
    const int col = lane & 15, quad = lane >> 4;
    const short* Ab = Act + (long)b * M * K;

    float4_ acc[4][4];
    #pragma unroll
    for (int i = 0; i < 4; ++i)
        #pragma unroll
        for (int j = 0; j < 4; ++j)
            acc[i][j] = (float4_){0.f, 0.f, 0.f, 0.f};

    const int arow = t >> 2, aseg = t & 3;
    for (int k0 = 0; k0 < K; k0 += 32) {
        __syncthreads();
        #pragma unroll
        for (int hh = 0; hh < 2; ++hh) {
            int row = arow + hh * 64;
            int gm = m0 + row;
            float4 av = make_float4(0.f, 0.f, 0.f, 0.f);
            if (gm < M) av = *(const float4*)(Ab + (long)gm * K + k0 + aseg * 8);
            *(float4*)(As + row * 40 + aseg * 8) = av;
            float4 bv = *(const float4*)(Wb + (long)(n0 + row) * K + k0 + aseg * 8);
            *(float4*)(Bs + row * 40 + aseg * 8) = bv;
        }
        __syncthreads();
        short8 af[4], bf[4];
        #pragma unroll
        for (int i = 0; i < 4; ++i)
            af[i] = *(const short8*)(As + (wm + i * 16 + col) * 40 + quad * 8);
        #pragma unroll
        for (int j = 0; j < 4; ++j)
            bf[j] = *(const short8*)(Bs + (wn + j * 16 + col) * 40 + quad * 8);
        #pragma unroll
        for (int i = 0; i < 4; ++i)
            #pragma unroll
            for (int j = 0; j < 4; ++j)
                acc[i][j] = __builtin_amdgcn_mfma_f32_16x16x32_bf16(af[i], bf[j], acc[i][j], 0, 0, 0);
    }

    float s1 = 0.f, s2s = 0.f;
    #pragma unroll
    for (int i = 0; i < 4; ++i) {
        int pbase = m0 + wm + i * 16 + quad * 4;
        #pragma unroll
        for (int j = 0; j < 4; ++j) {
            int oc = n0 + wn + j * 16 + col;
            if (EPI == 0) {
                float cb = bias[oc];
                #pragma unroll
                for (int r = 0; r < 4; ++r) {
                    int p = pbase + r;
                    if (p < M) outh[((long)b * M + p) * N + oc] = f2bf(acc[i][j][r] + cb);
                }
            } else if (EPI == 1) {
                float sc = g[oc] * rsqrtf(vv[oc] + EPS_);
                float sh = bb[oc] - mm[oc] * sc;
                float cb = bias[oc];
                #pragma unroll
                for (int r = 0; r < 4; ++r) {
                    int p = pbase + r;
                    if (p < M) outh[((long)b * M + p) * N + oc] =
                        f2bf(gelu_f((acc[i][j][r] + cb) * sc + sh));
                }
            } else if (EPI == 2) {
                float cb = bias[oc];
                if (pbase < M) {
                    #pragma unroll
                    for (int r = 0; r < 4; ++r) {
                        long jj = ((long)b * M + pbase + r) * 256 + oc;
                        float val = acc[i][j][r] + cb + res[jj];
                        outf[jj] = val;
                        s1 += val; s2s += val * val;
                    }
                }
            } else {
                float sc = g[oc] * rsqrtf(vv[oc] + EPS_);
                float sh = bb[oc] - mm[oc] * sc;
                float cb = bias[oc];
                if (pbase < M) {
                    long base = ((long)b * N + oc) * M + pbase;
                    float4 rv = *(const float4*)(res + base);
                    float4 y;
                    y.x = (acc[i][j][0] + cb) * sc + sh + rv.x;
                    y.y = (acc[i][j][1] + cb) * sc + sh + rv.y;
                    y.z = (acc[i][j][2] + cb) * sc + sh + rv.z;
                    y.w = (acc[i][j][3] + cb) * sc + sh + rv.w;
                    *(float4*)(outf + base) = y;
                }
            }
        }
    }
    if (EPI == 2) {
        #pragma unroll
        for (int o = 32; o > 0; o >>= 1) {
            s1 += __shfl_down(s1, o);
            s2s += __shfl_down(s2s, o);
        }
        if (lane == 0) {
            atomicAdd(&ostats[b * 2], s1);
            atomicAdd(&ostats[b * 2 + 1], s2s);
        }
    }
}

// ---- attention: online softmax, bf16 q/k/v pixel-major, float4 pos loads ----
__global__ __launch_bounds__(256) void attn_kernel(const short* __restrict__ q,
                                                   const short* __restrict__ k,
                                                   const short* __restrict__ v,
                                                   const float* __restrict__ pos_b,
                                                   short* __restrict__ out) {
    int qb4 = blockIdx.x & 3;
    int h = (blockIdx.x >> 2) & 7;
    int b = blockIdx.x >> 5;
    __shared__ float ks[NKPIX * 32];
    __shared__ float vs[NKPIX * 32];
    for (int idx = threadIdx.x; idx < NKPIX * 32; idx += 256) {
        int j = idx >> 5, d = idx & 31;
        long gi = ((long)(b * NKPIX + j)) * 256 + h * 32 + d;
        ks[idx] = bf2f(k[gi]);
        vs[idx] = bf2f(v[gi]);
    }
    __syncthreads();
    if (threadIdx.x >= 196) return;
    int iq = qb4 * 196 + threadIdx.x;
    float qr[32];
    const short* qp = q + ((long)(b * NPIX + iq)) * 256 + h * 32;
    #pragma unroll
    for (int d = 0; d < 32; ++d) qr[d] = bf2f(qp[d]);
    const float* pb = pos_b + ((long)h * NPIX + iq) * NKPIX;
    float m = -1e30f, l = 0.f, o[32];
    #pragma unroll
    for (int d = 0; d < 32; ++d) o[d] = 0.f;
    const float scale = 0.17677669529663689f;
    for (int j = 0; j < NKPIX; j += 4) {
        float4 pv = *(const float4*)(pb + j);
        float sc[4];
        #pragma unroll
        for (int u = 0; u < 4; ++u) {
            float s = 0.f;
            const float* kj = &ks[(j + u) * 32];
            #pragma unroll
            for (int d = 0; d < 32; ++d) s += qr[d] * kj[d];
            sc[u] = s * scale + ((const float*)&pv)[u];
        }
        float cmax = fmaxf(fmaxf(sc[0], sc[1]), fmaxf(sc[2], sc[3]));
        float nm = fmaxf(m, cmax);
        float alpha = __expf(m - nm);
        float p0 = __expf(sc[0] - nm), p1 = __expf(sc[1] - nm);
        float p2 = __expf(sc[2] - nm), p3 = __expf(sc[3] - nm);
        l = l * alpha + p0 + p1 + p2 + p3;
        const float* v0 = &vs[(j + 0) * 32];
        const float* v1 = &vs[(j + 1) * 32];
        const float* v2 = &vs[(j + 2) * 32];
        const float* v3 = &vs[(j + 3) * 32];
        #pragma unroll
        for (int d = 0; d < 32; ++d)
            o[d] = o[d] * alpha + p0 * v0[d] + p1 * v1[d] + p2 * v2[d] + p3 * v3[d];
        m = nm;
    }
    float inv = 1.f / l;
    short* op = out + ((long)(b * NPIX + iq)) * 256 + h * 32;
    #pragma unroll
    for (int d = 0; d < 32; ++d) op[d] = f2bf(o[d] * inv);
}

// ---- dwconv3x3 + BN2 + GELU: bf16 pixel-major t2 -> bf16 pixel-major t3 ----
__global__ void dwgelu_kernel(const short* __restrict__ t2, const float* __restrict__ dww,
                              const float* __restrict__ dwb, const float* __restrict__ g2,
                              const float* __restrict__ b2, const float* __restrict__ m2,
                              const float* __restrict__ v2, short* __restrict__ t3) {
    long idx = (long)blockIdx.x * 256 + threadIdx.x;
    int cm = (int)(idx & 1023);
    long rest = idx >> 10;
    int p = (int)(rest % NPIX);
    int b = (int)(rest / NPIX);
    int py = p / W_, px = p % W_;
    const short* tb = t2 + ((long)b * NPIX) * CM + cm;
    const float* wc = dww + cm * 9;
    float a = dwb[cm];
    #pragma unroll
    for (int dy = -1; dy <= 1; ++dy) {
        int yy = py + dy;
        if (yy < 0 || yy >= H_) continue;
        #pragma unroll
        for (int dx = -1; dx <= 1; ++dx) {
            int xc = px + dx;
            if (xc < 0 || xc >= W_) continue;
            a += wc[(dy + 1) * 3 + (dx + 1)] * bf2f(tb[(long)(yy * W_ + xc) * CM]);
        }
    }
    float sc = g2[cm] * rsqrtf(v2[cm] + EPS_);
    t3[idx] = f2bf(gelu_f(a * sc + (b2[cm] - m2[cm] * sc)));
}

extern "C" void kernel_launch(void* const* d_in, const int* in_sizes, int n_in,
                              void* d_out, int out_size, void* d_ws, size_t ws_size,
                              hipStream_t stream) {
    const float* x     = (const float*)d_in[0];
    const float* lpu_w = (const float*)d_in[1];
    const float* lpu_b = (const float*)d_in[2];
    const float* dw_w  = (const float*)d_in[3];
    const float* dw_b  = (const float*)d_in[4];
    const float* wq    = (const float*)d_in[5];
    const float* bq    = (const float*)d_in[6];
    const float* wk    = (const float*)d_in[7];
    const float* bk    = (const float*)d_in[8];
    const float* wv    = (const float*)d_in[9];
    const float* bv    = (const float*)d_in[10];
    const float* wo    = (const float*)d_in[11];
    const float* bo    = (const float*)d_in[12];
    const float* posb  = (const float*)d_in[13];
    const float* c1_w  = (const float*)d_in[14];
    const float* c1_b  = (const float*)d_in[15];
    const float* bn1_g = (const float*)d_in[16];
    const float* bn1_b = (const float*)d_in[17];
    const float* bn1_m = (const float*)d_in[18];
    const float* bn1_v = (const float*)d_in[19];
    const float* dw2_w = (const float*)d_in[20];
    const float* dw2_b = (const float*)d_in[21];
    const float* bn2_g = (const float*)d_in[22];
    const float* bn2_b = (const float*)d_in[23];
    const float* bn2_m = (const float*)d_in[24];
    const float* bn2_v = (const float*)d_in[25];
    const float* c2_w  = (const float*)d_in[26];
    const float* c2_b  = (const float*)d_in[27];
    const float* bn3_g = (const float*)d_in[28];
    const float* bn3_b = (const float*)d_in[29];
    const float* bn3_m = (const float*)d_in[30];
    const float* bn3_v = (const float*)d_in[31];

    const long n1  = (long)B_ * C_ * NPIX;    // 6,422,528
    const long nkv = (long)B_ * C_ * NKPIX;   // 1,605,632
    const long nm  = (long)B_ * CM * NPIX;    // 25,690,112

    char* base = (char*)d_ws;
    float* x1   = (float*)base; base += n1 * 4;
    float* x2c  = (float*)base; base += n1 * 4;
    short* x1n  = (short*)base; base += n1 * 2;
    short* qb   = (short*)base; base += n1 * 2;
    short* tmpb = (short*)base; base += n1 * 2;
    short* t1n  = (short*)base; base += n1 * 2;
    short* kvb  = (short*)base; base += nkv * 2;
    short* kb   = (short*)base; base += nkv * 2;
    short* vb   = (short*)base; base += nkv * 2;
    short* t2   = (short*)base; base += nm * 2;
    short* t3   = (short*)base; base += nm * 2;
    short* wbf  = (short*)base; base += 786432L * 2;
    float* stats = (float*)base;
    float* outp = (float*)d_out;

    zero_kernel<<<1, 128, 0, stream>>>(stats);
    wconv_kernel<<<3072, 256, 0, stream>>>(wq, wk, wv, wo, c1_w, c2_w, wbf);
    lpu_kernel<<<(int)(n1 / 256), 256, 0, stream>>>(x, lpu_w, lpu_b, x1, stats);
    kvconv_kernel<<<(int)((nkv + 255) / 256), 256, 0, stream>>>(x1, dw_w, dw_b, kvb);
    tln_kernel<<<dim3(25, 8, B_), 256, 0, stream>>>(x1, stats, x1n);
    // q/k/v projections
    mfma_gemm<0><<<dim3(7, 2, B_), 256, 0, stream>>>(
        x1n, wbf, NPIX, 256, 256, bq, nullptr, nullptr, nullptr, nullptr,
        nullptr, nullptr, qb, nullptr);
    mfma_gemm<0><<<dim3(2, 2, B_), 256, 0, stream>>>(
        kvb, wbf + 65536, NKPIX, 256, 256, bk, nullptr, nullptr, nullptr, nullptr,
        nullptr, nullptr, kb, nullptr);
    mfma_gemm<0><<<dim3(2, 2, B_), 256, 0, stream>>>(
        kvb, wbf + 131072, NKPIX, 256, 256, bv, nullptr, nullptr, nullptr, nullptr,
        nullptr, nullptr, vb, nullptr);
    attn_kernel<<<B_ * 32, 256, 0, stream>>>(qb, kb, vb, posb, tmpb);
    // wo + flat residual + LN2 stats
    mfma_gemm<2><<<dim3(7, 2, B_), 256, 0, stream>>>(
        tmpb, wbf + 196608, NPIX, 256, 256, bo, nullptr, nullptr, nullptr, nullptr,
        x1, stats + 64, nullptr, x2c);
    tln_kernel<<<dim3(25, 8, B_), 256, 0, stream>>>(x2c, stats + 64, t1n);
    // conv1 1x1 + BN1 + GELU
    mfma_gemm<1><<<dim3(7, 8, B_), 256, 0, stream>>>(
        t1n, wbf + 262144, NPIX, CM, 256, c1_b, bn1_g, bn1_b, bn1_m, bn1_v,
        nullptr, nullptr, t2, nullptr);
    dwgelu_kernel<<<(int)(nm / 256), 256, 0, stream>>>(
        t2, dw2_w, dw2_b, bn2_g, bn2_b, bn2_m, bn2_v, t3);
    // conv2 1x1 + BN3 + residual -> d_out (channel-major)
    mfma_gemm<3><<<dim3(7, 2, B_), 256, 0, stream>>>(
        t3, wbf + 524288, NPIX, 256, CM, c2_b, bn3_g, bn3_b, bn3_m, bn3_v,
        x2c, nullptr, nullptr, outp);
}

// Round 4
// 740.161 us; speedup vs baseline: 4.5299x; 1.5381x over previous
//
#include <hip/hip_runtime.h>
#include <math.h>

#define B_ 32
#define C_ 256
#define H_ 28
#define W_ 28
#define NPIX 784
#define HK 14
#define NKPIX 196
#define CM 1024
#define EPS_ 1e-5f
#define LN_INVN (1.0f / (C_ * NPIX))

typedef __attribute__((ext_vector_type(8))) short short8;
typedef __attribute__((ext_vector_type(4))) float float4_;

__device__ __forceinline__ float gelu_f(float x) {
    return 0.5f * x * (1.0f + erff(x * 0.70710678118654752f));
}
__device__ __forceinline__ short f2bf(float f) {
    union { float f; unsigned u; } x; x.f = f;
    unsigned r = x.u + 0x7FFF + ((x.u >> 16) & 1);
    return (short)(r >> 16);
}
__device__ __forceinline__ float bf2f(short s) {
    union { unsigned u; float f; } x; x.u = ((unsigned)(unsigned short)s) << 16;
    return x.f;
}

// ---- convert all 6 weight matrices to bf16 (layout [oc][k], k contiguous) ----
__global__ void wconv_kernel(const float* __restrict__ wq, const float* __restrict__ wk,
                             const float* __restrict__ wv, const float* __restrict__ wo,
                             const float* __restrict__ c1, const float* __restrict__ c2,
                             short* __restrict__ dst) {
    int idx = blockIdx.x * 256 + threadIdx.x;  // total 786432
    const float* src; int off;
    if (idx < 65536)       { src = wq; off = idx; }
    else if (idx < 131072) { src = wk; off = idx - 65536; }
    else if (idx < 196608) { src = wv; off = idx - 131072; }
    else if (idx < 262144) { src = wo; off = idx - 196608; }
    else if (idx < 524288) { src = c1; off = idx - 262144; }
    else                   { src = c2; off = idx - 524288; }
    dst[idx] = f2bf(src[off]);
}

// ---- generic LN stats reduce: 32 blocks, each folds cnt (sum,sumsq) pairs ----
__global__ void lnreduce_kernel(const float* __restrict__ part, int cnt,
                                float* __restrict__ out) {
    int b = blockIdx.x;
    const float* p = part + (long)b * cnt * 2;
    float s = 0.f, s2 = 0.f;
    for (int i = threadIdx.x; i < cnt; i += 256) {
        s += p[i * 2];
        s2 += p[i * 2 + 1];
    }
    #pragma unroll
    for (int o = 32; o > 0; o >>= 1) {
        s += __shfl_down(s, o);
        s2 += __shfl_down(s2, o);
    }
    __shared__ float ss[4][2];
    int wv = threadIdx.x >> 6;
    if ((threadIdx.x & 63) == 0) { ss[wv][0] = s; ss[wv][1] = s2; }
    __syncthreads();
    if (threadIdx.x == 0) {
        out[b * 2]     = ss[0][0] + ss[1][0] + ss[2][0] + ss[3][0];
        out[b * 2 + 1] = ss[0][1] + ss[1][1] + ss[2][1] + ss[3][1];
    }
}

// ---- LPU: depthwise 3x3 + bias + residual (fp32 channel-major), per-block LN1 partials ----
__global__ void lpu_kernel(const float* __restrict__ x, const float* __restrict__ w,
                           const float* __restrict__ bias, float* __restrict__ out,
                           float* __restrict__ part) {
    int idx = blockIdx.x * blockDim.x + threadIdx.x;
    int p = idx % NPIX;
    int c = (idx / NPIX) % C_;
    int y = p / W_, xx = p % W_;
    const float* xb = x + (size_t)(idx - p);
    const float* wc = w + c * 9;
    float acc = bias[c] + x[idx];
    #pragma unroll
    for (int dy = -1; dy <= 1; ++dy) {
        int yy = y + dy;
        if (yy < 0 || yy >= H_) continue;
        #pragma unroll
        for (int dx = -1; dx <= 1; ++dx) {
            int xc = xx + dx;
            if (xc < 0 || xc >= W_) continue;
            acc += wc[(dy + 1) * 3 + (dx + 1)] * xb[yy * W_ + xc];
        }
    }
    out[idx] = acc;
    float s = acc, s2 = acc * acc;
    #pragma unroll
    for (int o = 32; o > 0; o >>= 1) {
        s += __shfl_down(s, o);
        s2 += __shfl_down(s2, o);
    }
    __shared__ float ss[4][2];
    int wv = threadIdx.x >> 6;
    if ((threadIdx.x & 63) == 0) { ss[wv][0] = s; ss[wv][1] = s2; }
    __syncthreads();
    if (threadIdx.x == 0) {
        part[blockIdx.x * 2]     = ss[0][0] + ss[1][0] + ss[2][0] + ss[3][0];
        part[blockIdx.x * 2 + 1] = ss[0][1] + ss[1][1] + ss[2][1] + ss[3][1];
    }
}

// ---- transpose + LayerNorm: fp32 [b][256][784] -> bf16 [b][784][256] ----
__global__ void tln_kernel(const float* __restrict__ X, const float* __restrict__ st,
                           short* __restrict__ Y) {
    __shared__ float tile[32][33];
    int p0 = blockIdx.x * 32, c0 = blockIdx.y * 32, b = blockIdx.z;
    int tr = threadIdx.x >> 5, tc = threadIdx.x & 31;
    #pragma unroll
    for (int r = 0; r < 4; ++r) {
        int c = c0 + tr + r * 8, p = p0 + tc;
        tile[tr + r * 8][tc] = (p < NPIX) ? X[((long)b * C_ + c) * NPIX + p] : 0.f;
    }
    float sm = st[b * 2] * LN_INVN;
    float lr = rsqrtf(st[b * 2 + 1] * LN_INVN - sm * sm + EPS_);
    __syncthreads();
    #pragma unroll
    for (int r = 0; r < 4; ++r) {
        int p = p0 + tr + r * 8, c = c0 + tc;
        if (p < NPIX) Y[((long)b * NPIX + p) * C_ + c] = f2bf((tile[tc][tr + r * 8] - sm) * lr);
    }
}

// ---- kv depthwise 2x2 stride-2 (x1 fp32 channel-major -> bf16 pixel-major) ----
__global__ void kvconv_kernel(const float* __restrict__ x1, const float* __restrict__ w,
                              const float* __restrict__ bias, short* __restrict__ out) {
    int idx = blockIdx.x * 256 + threadIdx.x;
    if (idx >= B_ * NKPIX * C_) return;
    int c = idx & 255;
    int rest = idx >> 8;
    int p = rest % NKPIX;
    int b = rest / NKPIX;
    int yo = p / HK, xo = p % HK;
    const float* xb = x1 + ((long)b * C_ + c) * NPIX;
    const float* wc = w + c * 4;
    float a = bias[c]
            + wc[0] * xb[(2 * yo) * W_ + 2 * xo]     + wc[1] * xb[(2 * yo) * W_ + 2 * xo + 1]
            + wc[2] * xb[(2 * yo + 1) * W_ + 2 * xo] + wc[3] * xb[(2 * yo + 1) * W_ + 2 * xo + 1];
    out[idx] = f2bf(a);
}

// ---- MFMA GEMM: D[b][p][oc] = sum_k Act[b][p][k] * Wb[oc][k]  (bf16 in, fp32 acc) ----
// EPI 0: +bias -> bf16 out[b][p][oc]
// EPI 1: +bias, BN, GELU -> bf16 out[b][p][oc]
// EPI 2: +bias + res[flat p*256+oc] -> fp32 out same flat order, + per-wave LN partials
// EPI 3: +bias, BN, + res (channel-major) -> fp32 out channel-major [b][oc][p]
template <int EPI>
__global__ __launch_bounds__(256) void mfma_gemm(
    const short* __restrict__ Act, const short* __restrict__ Wb,
    int M, int N, int K,
    const float* __restrict__ bias,
    const float* __restrict__ g, const float* __restrict__ bb,
    const float* __restrict__ mm, const float* __restrict__ vv,
    const float* __restrict__ res, float* __restrict__ opart,
    short* __restrict__ outh, float* __restrict__ outf) {
    __shared__ short As[128 * 40];
    __shared__ short Bs[128 * 40];
    const int t = threadIdx.x;
    const int m0 = blockIdx.x * 128;
    const int n0 = blockIdx.y * 128;
    const int b = blockIdx.z;
    const int w = t >> 6, lane = t & 63;
    const int wm = (w & 1) * 64, wn = (w >> 1) * 64;
    const int col = lane & 15, quad = lane >> 4;
    const short* Ab = Act + (long)b * M * K;

    float4_ acc[4][4];
    #pragma unroll
    for (int i = 0; i < 4; ++i)
        #pragma unroll
        for (int j = 0; j < 4; ++j)
            acc[i][j] = (float4_){0.f, 0.f, 0.f, 0.f};

    const int arow = t >> 2, aseg = t & 3;
    for (int k0 = 0; k0 < K; k0 += 32) {
        __syncthreads();
        #pragma unroll
        for (int hh = 0; hh < 2; ++hh) {
            int row = arow + hh * 64;
            int gm = m0 + row;
            float4 av = make_float4(0.f, 0.f, 0.f, 0.f);
            if (gm < M) av = *(const float4*)(Ab + (long)gm * K + k0 + aseg * 8);
            *(float4*)(As + row * 40 + aseg * 8) = av;
            float4 bv = *(const float4*)(Wb + (long)(n0 + row) * K + k0 + aseg * 8);
            *(float4*)(Bs + row * 40 + aseg * 8) = bv;
        }
        __syncthreads();
        short8 af[4], bf[4];
        #pragma unroll
        for (int i = 0; i < 4; ++i)
            af[i] = *(const short8*)(As + (wm + i * 16 + col) * 40 + quad * 8);
        #pragma unroll
        for (int j = 0; j < 4; ++j)
            bf[j] = *(const short8*)(Bs + (wn + j * 16 + col) * 40 + quad * 8);
        #pragma unroll
        for (int i = 0; i < 4; ++i)
            #pragma unroll
            for (int j = 0; j < 4; ++j)
                acc[i][j] = __builtin_amdgcn_mfma_f32_16x16x32_bf16(af[i], bf[j], acc[i][j], 0, 0, 0);
    }

    float s1 = 0.f, s2s = 0.f;
    #pragma unroll
    for (int i = 0; i < 4; ++i) {
        int pbase = m0 + wm + i * 16 + quad * 4;
        #pragma unroll
        for (int j = 0; j < 4; ++j) {
            int oc = n0 + wn + j * 16 + col;
            if (EPI == 0) {
                float cb = bias[oc];
                #pragma unroll
                for (int r = 0; r < 4; ++r) {
                    int p = pbase + r;
                    if (p < M) outh[((long)b * M + p) * N + oc] = f2bf(acc[i][j][r] + cb);
                }
            } else if (EPI == 1) {
                float sc = g[oc] * rsqrtf(vv[oc] + EPS_);
                float sh = bb[oc] - mm[oc] * sc;
                float cb = bias[oc];
                #pragma unroll
                for (int r = 0; r < 4; ++r) {
                    int p = pbase + r;
                    if (p < M) outh[((long)b * M + p) * N + oc] =
                        f2bf(gelu_f((acc[i][j][r] + cb) * sc + sh));
                }
            } else if (EPI == 2) {
                float cb = bias[oc];
                if (pbase < M) {
                    #pragma unroll
                    for (int r = 0; r < 4; ++r) {
                        long jj = ((long)b * M + pbase + r) * 256 + oc;
                        float val = acc[i][j][r] + cb + res[jj];
                        outf[jj] = val;
                        s1 += val; s2s += val * val;
                    }
                }
            } else {
                float sc = g[oc] * rsqrtf(vv[oc] + EPS_);
                float sh = bb[oc] - mm[oc] * sc;
                float cb = bias[oc];
                if (pbase < M) {
                    long base = ((long)b * N + oc) * M + pbase;
                    float4 rv = *(const float4*)(res + base);
                    float4 y;
                    y.x = (acc[i][j][0] + cb) * sc + sh + rv.x;
                    y.y = (acc[i][j][1] + cb) * sc + sh + rv.y;
                    y.z = (acc[i][j][2] + cb) * sc + sh + rv.z;
                    y.w = (acc[i][j][3] + cb) * sc + sh + rv.w;
                    *(float4*)(outf + base) = y;
                }
            }
        }
    }
    if (EPI == 2) {
        #pragma unroll
        for (int o = 32; o > 0; o >>= 1) {
            s1 += __shfl_down(s1, o);
            s2s += __shfl_down(s2s, o);
        }
        if (lane == 0) {
            long slot = (((long)blockIdx.z * gridDim.y + blockIdx.y) * gridDim.x + blockIdx.x) * 4 + w;
            opart[slot * 2]     = s1;
            opart[slot * 2 + 1] = s2s;
        }
    }
}

// ---- attention: online softmax, bf16 q/k/v pixel-major, float4 pos loads ----
__global__ __launch_bounds__(256) void attn_kernel(const short* __restrict__ q,
                                                   const short* __restrict__ k,
                                                   const short* __restrict__ v,
                                                   const float* __restrict__ pos_b,
                                                   short* __restrict__ out) {
    int qb4 = blockIdx.x & 3;
    int h = (blockIdx.x >> 2) & 7;
    int b = blockIdx.x >> 5;
    __shared__ float ks[NKPIX * 32];
    __shared__ float vs[NKPIX * 32];
    for (int idx = threadIdx.x; idx < NKPIX * 32; idx += 256) {
        int j = idx >> 5, d = idx & 31;
        long gi = ((long)(b * NKPIX + j)) * 256 + h * 32 + d;
        ks[idx] = bf2f(k[gi]);
        vs[idx] = bf2f(v[gi]);
    }
    __syncthreads();
    if (threadIdx.x >= 196) return;
    int iq = qb4 * 196 + threadIdx.x;
    float qr[32];
    const short* qp = q + ((long)(b * NPIX + iq)) * 256 + h * 32;
    #pragma unroll
    for (int d = 0; d < 32; ++d) qr[d] = bf2f(qp[d]);
    const float* pb = pos_b + ((long)h * NPIX + iq) * NKPIX;
    float m = -1e30f, l = 0.f, o[32];
    #pragma unroll
    for (int d = 0; d < 32; ++d) o[d] = 0.f;
    const float scale = 0.17677669529663689f;
    for (int j = 0; j < NKPIX; j += 4) {
        float4 pv = *(const float4*)(pb + j);
        float sc[4];
        #pragma unroll
        for (int u = 0; u < 4; ++u) {
            float s = 0.f;
            const float* kj = &ks[(j + u) * 32];
            #pragma unroll
            for (int d = 0; d < 32; ++d) s += qr[d] * kj[d];
            sc[u] = s * scale + ((const float*)&pv)[u];
        }
        float cmax = fmaxf(fmaxf(sc[0], sc[1]), fmaxf(sc[2], sc[3]));
        float nm = fmaxf(m, cmax);
        float alpha = __expf(m - nm);
        float p0 = __expf(sc[0] - nm), p1 = __expf(sc[1] - nm);
        float p2 = __expf(sc[2] - nm), p3 = __expf(sc[3] - nm);
        l = l * alpha + p0 + p1 + p2 + p3;
        const float* v0 = &vs[(j + 0) * 32];
        const float* v1 = &vs[(j + 1) * 32];
        const float* v2 = &vs[(j + 2) * 32];
        const float* v3 = &vs[(j + 3) * 32];
        #pragma unroll
        for (int d = 0; d < 32; ++d)
            o[d] = o[d] * alpha + p0 * v0[d] + p1 * v1[d] + p2 * v2[d] + p3 * v3[d];
        m = nm;
    }
    float inv = 1.f / l;
    short* op = out + ((long)(b * NPIX + iq)) * 256 + h * 32;
    #pragma unroll
    for (int d = 0; d < 32; ++d) op[d] = f2bf(o[d] * inv);
}

// ---- dwconv3x3 + BN2 + GELU: bf16 pixel-major t2 -> bf16 pixel-major t3 ----
__global__ void dwgelu_kernel(const short* __restrict__ t2, const float* __restrict__ dww,
                              const float* __restrict__ dwb, const float* __restrict__ g2,
                              const float* __restrict__ b2, const float* __restrict__ m2,
                              const float* __restrict__ v2, short* __restrict__ t3) {
    long idx = (long)blockIdx.x * 256 + threadIdx.x;
    int cm = (int)(idx & 1023);
    long rest = idx >> 10;
    int p = (int)(rest % NPIX);
    int b = (int)(rest / NPIX);
    int py = p / W_, px = p % W_;
    const short* tb = t2 + ((long)b * NPIX) * CM + cm;
    const float* wc = dww + cm * 9;
    float a = dwb[cm];
    #pragma unroll
    for (int dy = -1; dy <= 1; ++dy) {
        int yy = py + dy;
        if (yy < 0 || yy >= H_) continue;
        #pragma unroll
        for (int dx = -1; dx <= 1; ++dx) {
            int xc = px + dx;
            if (xc < 0 || xc >= W_) continue;
            a += wc[(dy + 1) * 3 + (dx + 1)] * bf2f(tb[(long)(yy * W_ + xc) * CM]);
        }
    }
    float sc = g2[cm] * rsqrtf(v2[cm] + EPS_);
    t3[idx] = f2bf(gelu_f(a * sc + (b2[cm] - m2[cm] * sc)));
}

extern "C" void kernel_launch(void* const* d_in, const int* in_sizes, int n_in,
                              void* d_out, int out_size, void* d_ws, size_t ws_size,
                              hipStream_t stream) {
    const float* x     = (const float*)d_in[0];
    const float* lpu_w = (const float*)d_in[1];
    const float* lpu_b = (const float*)d_in[2];
    const float* dw_w  = (const float*)d_in[3];
    const float* dw_b  = (const float*)d_in[4];
    const float* wq    = (const float*)d_in[5];
    const float* bq    = (const float*)d_in[6];
    const float* wk    = (const float*)d_in[7];
    const float* bk    = (const float*)d_in[8];
    const float* wv    = (const float*)d_in[9];
    const float* bv    = (const float*)d_in[10];
    const float* wo    = (const float*)d_in[11];
    const float* bo    = (const float*)d_in[12];
    const float* posb  = (const float*)d_in[13];
    const float* c1_w  = (const float*)d_in[14];
    const float* c1_b  = (const float*)d_in[15];
    const float* bn1_g = (const float*)d_in[16];
    const float* bn1_b = (const float*)d_in[17];
    const float* bn1_m = (const float*)d_in[18];
    const float* bn1_v = (const float*)d_in[19];
    const float* dw2_w = (const float*)d_in[20];
    const float* dw2_b = (const float*)d_in[21];
    const float* bn2_g = (const float*)d_in[22];
    const float* bn2_b = (const float*)d_in[23];
    const float* bn2_m = (const float*)d_in[24];
    const float* bn2_v = (const float*)d_in[25];
    const float* c2_w  = (const float*)d_in[26];
    const float* c2_b  = (const float*)d_in[27];
    const float* bn3_g = (const float*)d_in[28];
    const float* bn3_b = (const float*)d_in[29];
    const float* bn3_m = (const float*)d_in[30];
    const float* bn3_v = (const float*)d_in[31];

    const long n1  = (long)B_ * C_ * NPIX;    // 6,422,528
    const long nkv = (long)B_ * C_ * NKPIX;   // 1,605,632
    const long nm  = (long)B_ * CM * NPIX;    // 25,690,112
    const int  nblk1 = (int)(n1 / 256);       // 25088 lpu blocks (784 per sample)

    char* base = (char*)d_ws;
    float* x1   = (float*)base; base += n1 * 4;
    float* x2c  = (float*)base; base += n1 * 4;
    short* x1n  = (short*)base; base += n1 * 2;
    short* qb   = (short*)base; base += n1 * 2;
    short* tmpb = (short*)base; base += n1 * 2;
    short* t1n  = (short*)base; base += n1 * 2;
    short* kvb  = (short*)base; base += nkv * 2;
    short* kb   = (short*)base; base += nkv * 2;
    short* vb   = (short*)base; base += nkv * 2;
    short* t2   = (short*)base; base += nm * 2;
    short* t3   = (short*)base; base += nm * 2;
    short* wbf  = (short*)base; base += 786432L * 2;
    float* stats = (float*)base; base += 128 * 4;
    float* part1 = (float*)base; base += (long)nblk1 * 2 * 4;
    float* part2 = (float*)base;
    float* outp = (float*)d_out;

    wconv_kernel<<<3072, 256, 0, stream>>>(wq, wk, wv, wo, c1_w, c2_w, wbf);
    lpu_kernel<<<nblk1, 256, 0, stream>>>(x, lpu_w, lpu_b, x1, part1);
    lnreduce_kernel<<<B_, 256, 0, stream>>>(part1, nblk1 / B_, stats);
    kvconv_kernel<<<(int)((nkv + 255) / 256), 256, 0, stream>>>(x1, dw_w, dw_b, kvb);
    tln_kernel<<<dim3(25, 8, B_), 256, 0, stream>>>(x1, stats, x1n);
    // q/k/v projections
    mfma_gemm<0><<<dim3(7, 2, B_), 256, 0, stream>>>(
        x1n, wbf, NPIX, 256, 256, bq, nullptr, nullptr, nullptr, nullptr,
        nullptr, nullptr, qb, nullptr);
    mfma_gemm<0><<<dim3(2, 2, B_), 256, 0, stream>>>(
        kvb, wbf + 65536, NKPIX, 256, 256, bk, nullptr, nullptr, nullptr, nullptr,
        nullptr, nullptr, kb, nullptr);
    mfma_gemm<0><<<dim3(2, 2, B_), 256, 0, stream>>>(
        kvb, wbf + 131072, NKPIX, 256, 256, bv, nullptr, nullptr, nullptr, nullptr,
        nullptr, nullptr, vb, nullptr);
    attn_kernel<<<B_ * 32, 256, 0, stream>>>(qb, kb, vb, posb, tmpb);
    // wo + flat residual + per-wave LN2 partials (grid 7x2x32 -> 56 slots per b)
    mfma_gemm<2><<<dim3(7, 2, B_), 256, 0, stream>>>(
        tmpb, wbf + 196608, NPIX, 256, 256, bo, nullptr, nullptr, nullptr, nullptr,
        x1, part2, nullptr, x2c);
    lnreduce_kernel<<<B_, 256, 0, stream>>>(part2, 56, stats + 64);
    tln_kernel<<<dim3(25, 8, B_), 256, 0, stream>>>(x2c, stats + 64, t1n);
    // conv1 1x1 + BN1 + GELU
    mfma_gemm<1><<<dim3(7, 8, B_), 256, 0, stream>>>(
        t1n, wbf + 262144, NPIX, CM, 256, c1_b, bn1_g, bn1_b, bn1_m, bn1_v,
        nullptr, nullptr, t2, nullptr);
    dwgelu_kernel<<<(int)(nm / 256), 256, 0, stream>>>(
        t2, dw2_w, dw2_b, bn2_g, bn2_b, bn2_m, bn2_v, t3);
    // conv2 1x1 + BN3 + residual -> d_out (channel-major)
    mfma_gemm<3><<<dim3(7, 2, B_), 256, 0, stream>>>(
        t3, wbf + 524288, NPIX, 256, CM, c2_b, bn3_g, bn3_b, bn3_m, bn3_v,
        x2c, nullptr, nullptr, outp);
}

// Round 5
// 586.757 us; speedup vs baseline: 5.7142x; 1.2614x over previous
//
#include <hip/hip_runtime.h>
#include <math.h>

#define B_ 32
#define C_ 256
#define H_ 28
#define W_ 28
#define NPIX 784
#define HK 14
#define NKPIX 196
#define CM 1024
#define EPS_ 1e-5f
#define LN_INVN (1.0f / (C_ * NPIX))

typedef __attribute__((ext_vector_type(8))) short short8;
typedef __attribute__((ext_vector_type(4))) float float4_;

__device__ __forceinline__ float gelu_f(float x) {
    return 0.5f * x * (1.0f + erff(x * 0.70710678118654752f));
}
__device__ __forceinline__ short f2bf(float f) {
    union { float f; unsigned u; } x; x.f = f;
    unsigned r = x.u + 0x7FFF + ((x.u >> 16) & 1);
    return (short)(r >> 16);
}
__device__ __forceinline__ float bf2f(short s) {
    union { unsigned u; float f; } x; x.u = ((unsigned)(unsigned short)s) << 16;
    return x.f;
}

// ---- convert all 6 weight matrices to bf16 (layout [oc][k], k contiguous) ----
__global__ void wconv_kernel(const float* __restrict__ wq, const float* __restrict__ wk,
                             const float* __restrict__ wv, const float* __restrict__ wo,
                             const float* __restrict__ c1, const float* __restrict__ c2,
                             short* __restrict__ dst) {
    int idx = blockIdx.x * 256 + threadIdx.x;  // total 786432
    const float* src; int off;
    if (idx < 65536)       { src = wq; off = idx; }
    else if (idx < 131072) { src = wk; off = idx - 65536; }
    else if (idx < 196608) { src = wv; off = idx - 131072; }
    else if (idx < 262144) { src = wo; off = idx - 196608; }
    else if (idx < 524288) { src = c1; off = idx - 262144; }
    else                   { src = c2; off = idx - 524288; }
    dst[idx] = f2bf(src[off]);
}

// ---- prep for dwgelu: transpose dww to [tap][1024], fold dwb+BN2 to (sc,sh) ----
__global__ void dwprep_kernel(const float* __restrict__ dww, const float* __restrict__ dwb,
                              const float* __restrict__ g2, const float* __restrict__ b2,
                              const float* __restrict__ m2, const float* __restrict__ v2,
                              float* __restrict__ wt, float* __restrict__ sc2,
                              float* __restrict__ sh2) {
    int cm = blockIdx.x * 256 + threadIdx.x;  // 1024
    float sc = g2[cm] * rsqrtf(v2[cm] + EPS_);
    sc2[cm] = sc;
    sh2[cm] = (dwb[cm] - m2[cm]) * sc + b2[cm];
    #pragma unroll
    for (int tap = 0; tap < 9; ++tap) wt[tap * 1024 + cm] = dww[cm * 9 + tap];
}

// ---- generic LN stats reduce: 32 blocks, each folds cnt (sum,sumsq) pairs ----
__global__ void lnreduce_kernel(const float* __restrict__ part, int cnt,
                                float* __restrict__ out) {
    int b = blockIdx.x;
    const float* p = part + (long)b * cnt * 2;
    float s = 0.f, s2 = 0.f;
    for (int i = threadIdx.x; i < cnt; i += 256) {
        s += p[i * 2];
        s2 += p[i * 2 + 1];
    }
    #pragma unroll
    for (int o = 32; o > 0; o >>= 1) {
        s += __shfl_down(s, o);
        s2 += __shfl_down(s2, o);
    }
    __shared__ float ss[4][2];
    int wv = threadIdx.x >> 6;
    if ((threadIdx.x & 63) == 0) { ss[wv][0] = s; ss[wv][1] = s2; }
    __syncthreads();
    if (threadIdx.x == 0) {
        out[b * 2]     = ss[0][0] + ss[1][0] + ss[2][0] + ss[3][0];
        out[b * 2 + 1] = ss[0][1] + ss[1][1] + ss[2][1] + ss[3][1];
    }
}

// ---- LPU: depthwise 3x3 + bias + residual (fp32 channel-major), per-block LN1 partials ----
__global__ void lpu_kernel(const float* __restrict__ x, const float* __restrict__ w,
                           const float* __restrict__ bias, float* __restrict__ out,
                           float* __restrict__ part) {
    int idx = blockIdx.x * blockDim.x + threadIdx.x;
    int p = idx % NPIX;
    int c = (idx / NPIX) % C_;
    int y = p / W_, xx = p % W_;
    const float* xb = x + (size_t)(idx - p);
    const float* wc = w + c * 9;
    float acc = bias[c] + x[idx];
    #pragma unroll
    for (int dy = -1; dy <= 1; ++dy) {
        int yy = y + dy;
        if (yy < 0 || yy >= H_) continue;
        #pragma unroll
        for (int dx = -1; dx <= 1; ++dx) {
            int xc = xx + dx;
            if (xc < 0 || xc >= W_) continue;
            acc += wc[(dy + 1) * 3 + (dx + 1)] * xb[yy * W_ + xc];
        }
    }
    out[idx] = acc;
    float s = acc, s2 = acc * acc;
    #pragma unroll
    for (int o = 32; o > 0; o >>= 1) {
        s += __shfl_down(s, o);
        s2 += __shfl_down(s2, o);
    }
    __shared__ float ss[4][2];
    int wv = threadIdx.x >> 6;
    if ((threadIdx.x & 63) == 0) { ss[wv][0] = s; ss[wv][1] = s2; }
    __syncthreads();
    if (threadIdx.x == 0) {
        part[blockIdx.x * 2]     = ss[0][0] + ss[1][0] + ss[2][0] + ss[3][0];
        part[blockIdx.x * 2 + 1] = ss[0][1] + ss[1][1] + ss[2][1] + ss[3][1];
    }
}

// ---- transpose + LayerNorm: fp32 [b][256][784] -> bf16 [b][784][256] ----
__global__ void tln_kernel(const float* __restrict__ X, const float* __restrict__ st,
                           short* __restrict__ Y) {
    __shared__ float tile[32][33];
    int p0 = blockIdx.x * 32, c0 = blockIdx.y * 32, b = blockIdx.z;
    int tr = threadIdx.x >> 5, tc = threadIdx.x & 31;
    #pragma unroll
    for (int r = 0; r < 4; ++r) {
        int c = c0 + tr + r * 8, p = p0 + tc;
        tile[tr + r * 8][tc] = (p < NPIX) ? X[((long)b * C_ + c) * NPIX + p] : 0.f;
    }
    float sm = st[b * 2] * LN_INVN;
    float lr = rsqrtf(st[b * 2 + 1] * LN_INVN - sm * sm + EPS_);
    __syncthreads();
    #pragma unroll
    for (int r = 0; r < 4; ++r) {
        int p = p0 + tr + r * 8, c = c0 + tc;
        if (p < NPIX) Y[((long)b * NPIX + p) * C_ + c] = f2bf((tile[tc][tr + r * 8] - sm) * lr);
    }
}

// ---- kv depthwise 2x2 stride-2 (x1 fp32 channel-major -> bf16 pixel-major) ----
__global__ void kvconv_kernel(const float* __restrict__ x1, const float* __restrict__ w,
                              const float* __restrict__ bias, short* __restrict__ out) {
    int idx = blockIdx.x * 256 + threadIdx.x;
    if (idx >= B_ * NKPIX * C_) return;
    int c = idx & 255;
    int rest = idx >> 8;
    int p = rest % NKPIX;
    int b = rest / NKPIX;
    int yo = p / HK, xo = p % HK;
    const float* xb = x1 + ((long)b * C_ + c) * NPIX;
    const float* wc = w + c * 4;
    float a = bias[c]
            + wc[0] * xb[(2 * yo) * W_ + 2 * xo]     + wc[1] * xb[(2 * yo) * W_ + 2 * xo + 1]
            + wc[2] * xb[(2 * yo + 1) * W_ + 2 * xo] + wc[3] * xb[(2 * yo + 1) * W_ + 2 * xo + 1];
    out[idx] = f2bf(a);
}

// ---- MFMA GEMM: D[b][p][oc] = sum_k Act[b][p][k] * Wb[oc][k]  (bf16 in, fp32 acc) ----
template <int EPI>
__global__ __launch_bounds__(256) void mfma_gemm(
    const short* __restrict__ Act, const short* __restrict__ Wb,
    int M, int N, int K,
    const float* __restrict__ bias,
    const float* __restrict__ g, const float* __restrict__ bb,
    const float* __restrict__ mm, const float* __restrict__ vv,
    const float* __restrict__ res, float* __restrict__ opart,
    short* __restrict__ outh, float* __restrict__ outf) {
    __shared__ short As[128 * 40];
    __shared__ short Bs[128 * 40];
    const int t = threadIdx.x;
    const int m0 = blockIdx.x * 128;
    const int n0 = blockIdx.y * 128;
    const int b = blockIdx.z;
    const int w = t >> 6, lane = t & 63;
    const int wm = (w & 1) * 64, wn = (w >> 1) * 64;
    const int col = lane & 15, quad = lane >> 4;
    const short* Ab = Act + (long)b * M * K;

    float4_ acc[4][4];
    #pragma unroll
    for (int i = 0; i < 4; ++i)
        #pragma unroll
        for (int j = 0; j < 4; ++j)
            acc[i][j] = (float4_){0.f, 0.f, 0.f, 0.f};

    const int arow = t >> 2, aseg = t & 3;
    for (int k0 = 0; k0 < K; k0 += 32) {
        __syncthreads();
        #pragma unroll
        for (int hh = 0; hh < 2; ++hh) {
            int row = arow + hh * 64;
            int gm = m0 + row;
            float4 av = make_float4(0.f, 0.f, 0.f, 0.f);
            if (gm < M) av = *(const float4*)(Ab + (long)gm * K + k0 + aseg * 8);
            *(float4*)(As + row * 40 + aseg * 8) = av;
            float4 bv = *(const float4*)(Wb + (long)(n0 + row) * K + k0 + aseg * 8);
            *(float4*)(Bs + row * 40 + aseg * 8) = bv;
        }
        __syncthreads();
        short8 af[4], bf[4];
        #pragma unroll
        for (int i = 0; i < 4; ++i)
            af[i] = *(const short8*)(As + (wm + i * 16 + col) * 40 + quad * 8);
        #pragma unroll
        for (int j = 0; j < 4; ++j)
            bf[j] = *(const short8*)(Bs + (wn + j * 16 + col) * 40 + quad * 8);
        #pragma unroll
        for (int i = 0; i < 4; ++i)
            #pragma unroll
            for (int j = 0; j < 4; ++j)
                acc[i][j] = __builtin_amdgcn_mfma_f32_16x16x32_bf16(af[i], bf[j], acc[i][j], 0, 0, 0);
    }

    float s1 = 0.f, s2s = 0.f;
    #pragma unroll
    for (int i = 0; i < 4; ++i) {
        int pbase = m0 + wm + i * 16 + quad * 4;
        #pragma unroll
        for (int j = 0; j < 4; ++j) {
            int oc = n0 + wn + j * 16 + col;
            if (EPI == 0) {
                float cb = bias[oc];
                #pragma unroll
                for (int r = 0; r < 4; ++r) {
                    int p = pbase + r;
                    if (p < M) outh[((long)b * M + p) * N + oc] = f2bf(acc[i][j][r] + cb);
                }
            } else if (EPI == 1) {
                float sc = g[oc] * rsqrtf(vv[oc] + EPS_);
                float sh = bb[oc] - mm[oc] * sc;
                float cb = bias[oc];
                #pragma unroll
                for (int r = 0; r < 4; ++r) {
                    int p = pbase + r;
                    if (p < M) outh[((long)b * M + p) * N + oc] =
                        f2bf(gelu_f((acc[i][j][r] + cb) * sc + sh));
                }
            } else if (EPI == 2) {
                float cb = bias[oc];
                if (pbase < M) {
                    #pragma unroll
                    for (int r = 0; r < 4; ++r) {
                        long jj = ((long)b * M + pbase + r) * 256 + oc;
                        float val = acc[i][j][r] + cb + res[jj];
                        outf[jj] = val;
                        s1 += val; s2s += val * val;
                    }
                }
            } else {
                float sc = g[oc] * rsqrtf(vv[oc] + EPS_);
                float sh = bb[oc] - mm[oc] * sc;
                float cb = bias[oc];
                if (pbase < M) {
                    long base = ((long)b * N + oc) * M + pbase;
                    float4 rv = *(const float4*)(res + base);
                    float4 y;
                    y.x = (acc[i][j][0] + cb) * sc + sh + rv.x;
                    y.y = (acc[i][j][1] + cb) * sc + sh + rv.y;
                    y.z = (acc[i][j][2] + cb) * sc + sh + rv.z;
                    y.w = (acc[i][j][3] + cb) * sc + sh + rv.w;
                    *(float4*)(outf + base) = y;
                }
            }
        }
    }
    if (EPI == 2) {
        #pragma unroll
        for (int o = 32; o > 0; o >>= 1) {
            s1 += __shfl_down(s1, o);
            s2s += __shfl_down(s2s, o);
        }
        if (lane == 0) {
            long slot = (((long)blockIdx.z * gridDim.y + blockIdx.y) * gridDim.x + blockIdx.x) * 4 + w;
            opart[slot * 2]     = s1;
            opart[slot * 2 + 1] = s2s;
        }
    }
}

// ---- attention: online softmax, float4 LDS reads (broadcast), float4 pos loads ----
__global__ __launch_bounds__(256) void attn_kernel(const short* __restrict__ q,
                                                   const short* __restrict__ k,
                                                   const short* __restrict__ v,
                                                   const float* __restrict__ pos_b,
                                                   short* __restrict__ out) {
    int qb4 = blockIdx.x & 3;
    int h = (blockIdx.x >> 2) & 7;
    int b = blockIdx.x >> 5;
    __shared__ float ks[NKPIX * 32];
    __shared__ float vs[NKPIX * 32];
    for (int idx = threadIdx.x; idx < NKPIX * 32; idx += 256) {
        int j = idx >> 5, d = idx & 31;
        long gi = ((long)(b * NKPIX + j)) * 256 + h * 32 + d;
        ks[idx] = bf2f(k[gi]);
        vs[idx] = bf2f(v[gi]);
    }
    __syncthreads();
    if (threadIdx.x >= 196) return;
    const float4* ks4 = (const float4*)ks;
    const float4* vs4 = (const float4*)vs;
    int iq = qb4 * 196 + threadIdx.x;
    float4 qr[8];
    const short* qp = q + ((long)(b * NPIX + iq)) * 256 + h * 32;
    #pragma unroll
    for (int d4 = 0; d4 < 8; ++d4) {
        qr[d4].x = bf2f(qp[d4 * 4 + 0]);
        qr[d4].y = bf2f(qp[d4 * 4 + 1]);
        qr[d4].z = bf2f(qp[d4 * 4 + 2]);
        qr[d4].w = bf2f(qp[d4 * 4 + 3]);
    }
    const float* pb = pos_b + ((long)h * NPIX + iq) * NKPIX;
    float m = -1e30f, l = 0.f;
    float4 o4[8];
    #pragma unroll
    for (int d4 = 0; d4 < 8; ++d4) o4[d4] = make_float4(0.f, 0.f, 0.f, 0.f);
    const float scale = 0.17677669529663689f;
    for (int j = 0; j < NKPIX; j += 4) {
        float4 pv = *(const float4*)(pb + j);
        float sc[4];
        #pragma unroll
        for (int u = 0; u < 4; ++u) {
            float4 sa = make_float4(0.f, 0.f, 0.f, 0.f);
            #pragma unroll
            for (int d4 = 0; d4 < 8; ++d4) {
                float4 kv = ks4[(j + u) * 8 + d4];
                sa.x += qr[d4].x * kv.x;
                sa.y += qr[d4].y * kv.y;
                sa.z += qr[d4].z * kv.z;
                sa.w += qr[d4].w * kv.w;
            }
            sc[u] = (sa.x + sa.y + sa.z + sa.w) * scale + ((const float*)&pv)[u];
        }
        float cmax = fmaxf(fmaxf(sc[0], sc[1]), fmaxf(sc[2], sc[3]));
        float nm = fmaxf(m, cmax);
        float alpha = __expf(m - nm);
        float p0 = __expf(sc[0] - nm), p1 = __expf(sc[1] - nm);
        float p2 = __expf(sc[2] - nm), p3 = __expf(sc[3] - nm);
        l = l * alpha + p0 + p1 + p2 + p3;
        #pragma unroll
        for (int d4 = 0; d4 < 8; ++d4) {
            float4 v0 = vs4[(j + 0) * 8 + d4];
            float4 v1 = vs4[(j + 1) * 8 + d4];
            float4 v2 = vs4[(j + 2) * 8 + d4];
            float4 v3 = vs4[(j + 3) * 8 + d4];
            o4[d4].x = o4[d4].x * alpha + p0 * v0.x + p1 * v1.x + p2 * v2.x + p3 * v3.x;
            o4[d4].y = o4[d4].y * alpha + p0 * v0.y + p1 * v1.y + p2 * v2.y + p3 * v3.y;
            o4[d4].z = o4[d4].z * alpha + p0 * v0.z + p1 * v1.z + p2 * v2.z + p3 * v3.z;
            o4[d4].w = o4[d4].w * alpha + p0 * v0.w + p1 * v1.w + p2 * v2.w + p3 * v3.w;
        }
        m = nm;
    }
    float inv = 1.f / l;
    short8 ov[4];
    #pragma unroll
    for (int d4 = 0; d4 < 8; ++d4) {
        ((short*)ov)[d4 * 4 + 0] = f2bf(o4[d4].x * inv);
        ((short*)ov)[d4 * 4 + 1] = f2bf(o4[d4].y * inv);
        ((short*)ov)[d4 * 4 + 2] = f2bf(o4[d4].z * inv);
        ((short*)ov)[d4 * 4 + 3] = f2bf(o4[d4].w * inv);
    }
    short* op = out + ((long)(b * NPIX + iq)) * 256 + h * 32;
    #pragma unroll
    for (int i = 0; i < 4; ++i) *(short8*)(op + i * 8) = ov[i];
}

// ---- dwconv3x3 + BN2 + GELU, 8 channels/thread via short8 ----
// t2 bf16 [b][p][1024] -> t3 bf16 [b][p][1024]; wt [tap][1024]; sc/sh [1024]
__global__ __launch_bounds__(256) void dwgelu_kernel(
    const short* __restrict__ t2, const float* __restrict__ wt,
    const float* __restrict__ sc2, const float* __restrict__ sh2,
    short* __restrict__ t3) {
    int idx = blockIdx.x * 256 + threadIdx.x;  // B*NPIX*128 = 3,211,264
    int cm8 = idx & 127;
    int rest = idx >> 7;
    int p = rest % NPIX;
    int b = rest / NPIX;
    int py = p / W_, px = p % W_;
    int cm0 = cm8 * 8;
    const short* tb = t2 + ((long)b * NPIX) * CM + cm0;
    float acc[8];
    #pragma unroll
    for (int r = 0; r < 8; ++r) acc[r] = 0.f;
    #pragma unroll
    for (int dy = -1; dy <= 1; ++dy) {
        int yy = py + dy;
        if (yy < 0 || yy >= H_) continue;
        #pragma unroll
        for (int dx = -1; dx <= 1; ++dx) {
            int xc = px + dx;
            if (xc < 0 || xc >= W_) continue;
            int tap = (dy + 1) * 3 + (dx + 1);
            short8 tv = *(const short8*)(tb + (long)(yy * W_ + xc) * CM);
            float4 w0 = *(const float4*)(wt + tap * 1024 + cm0);
            float4 w1 = *(const float4*)(wt + tap * 1024 + cm0 + 4);
            acc[0] += bf2f(tv[0]) * w0.x;
            acc[1] += bf2f(tv[1]) * w0.y;
            acc[2] += bf2f(tv[2]) * w0.z;
            acc[3] += bf2f(tv[3]) * w0.w;
            acc[4] += bf2f(tv[4]) * w1.x;
            acc[5] += bf2f(tv[5]) * w1.y;
            acc[6] += bf2f(tv[6]) * w1.z;
            acc[7] += bf2f(tv[7]) * w1.w;
        }
    }
    float4 sa = *(const float4*)(sc2 + cm0);
    float4 sb = *(const float4*)(sc2 + cm0 + 4);
    float4 ha = *(const float4*)(sh2 + cm0);
    float4 hb = *(const float4*)(sh2 + cm0 + 4);
    short8 ov;
    ov[0] = f2bf(gelu_f(acc[0] * sa.x + ha.x));
    ov[1] = f2bf(gelu_f(acc[1] * sa.y + ha.y));
    ov[2] = f2bf(gelu_f(acc[2] * sa.z + ha.z));
    ov[3] = f2bf(gelu_f(acc[3] * sa.w + ha.w));
    ov[4] = f2bf(gelu_f(acc[4] * sb.x + hb.x));
    ov[5] = f2bf(gelu_f(acc[5] * sb.y + hb.y));
    ov[6] = f2bf(gelu_f(acc[6] * sb.z + hb.z));
    ov[7] = f2bf(gelu_f(acc[7] * sb.w + hb.w));
    *(short8*)(t3 + ((long)b * NPIX + p) * CM + cm0) = ov;
}

extern "C" void kernel_launch(void* const* d_in, const int* in_sizes, int n_in,
                              void* d_out, int out_size, void* d_ws, size_t ws_size,
                              hipStream_t stream) {
    const float* x     = (const float*)d_in[0];
    const float* lpu_w = (const float*)d_in[1];
    const float* lpu_b = (const float*)d_in[2];
    const float* dw_w  = (const float*)d_in[3];
    const float* dw_b  = (const float*)d_in[4];
    const float* wq    = (const float*)d_in[5];
    const float* bq    = (const float*)d_in[6];
    const float* wk    = (const float*)d_in[7];
    const float* bk    = (const float*)d_in[8];
    const float* wv    = (const float*)d_in[9];
    const float* bv    = (const float*)d_in[10];
    const float* wo    = (const float*)d_in[11];
    const float* bo    = (const float*)d_in[12];
    const float* posb  = (const float*)d_in[13];
    const float* c1_w  = (const float*)d_in[14];
    const float* c1_b  = (const float*)d_in[15];
    const float* bn1_g = (const float*)d_in[16];
    const float* bn1_b = (const float*)d_in[17];
    const float* bn1_m = (const float*)d_in[18];
    const float* bn1_v = (const float*)d_in[19];
    const float* dw2_w = (const float*)d_in[20];
    const float* dw2_b = (const float*)d_in[21];
    const float* bn2_g = (const float*)d_in[22];
    const float* bn2_b = (const float*)d_in[23];
    const float* bn2_m = (const float*)d_in[24];
    const float* bn2_v = (const float*)d_in[25];
    const float* c2_w  = (const float*)d_in[26];
    const float* c2_b  = (const float*)d_in[27];
    const float* bn3_g = (const float*)d_in[28];
    const float* bn3_b = (const float*)d_in[29];
    const float* bn3_m = (const float*)d_in[30];
    const float* bn3_v = (const float*)d_in[31];

    const long n1  = (long)B_ * C_ * NPIX;    // 6,422,528
    const long nkv = (long)B_ * C_ * NKPIX;   // 1,605,632
    const long nm  = (long)B_ * CM * NPIX;    // 25,690,112
    const int  nblk1 = (int)(n1 / 256);       // 25088 lpu blocks (784 per sample)

    char* base = (char*)d_ws;
    float* x1   = (float*)base; base += n1 * 4;
    float* x2c  = (float*)base; base += n1 * 4;
    short* x1n  = (short*)base; base += n1 * 2;
    short* qb   = (short*)base; base += n1 * 2;
    short* tmpb = (short*)base; base += n1 * 2;
    short* t1n  = (short*)base; base += n1 * 2;
    short* kvb  = (short*)base; base += nkv * 2;
    short* kb   = (short*)base; base += nkv * 2;
    short* vb   = (short*)base; base += nkv * 2;
    short* t2   = (short*)base; base += nm * 2;
    short* t3   = (short*)base; base += nm * 2;
    short* wbf  = (short*)base; base += 786432L * 2;
    float* stats = (float*)base; base += 128 * 4;
    float* dwt   = (float*)base; base += 9216 * 4;   // [9][1024]
    float* dsc   = (float*)base; base += 1024 * 4;
    float* dsh   = (float*)base; base += 1024 * 4;
    float* part1 = (float*)base; base += (long)nblk1 * 2 * 4;
    float* part2 = (float*)base;
    float* outp = (float*)d_out;

    wconv_kernel<<<3072, 256, 0, stream>>>(wq, wk, wv, wo, c1_w, c2_w, wbf);
    dwprep_kernel<<<4, 256, 0, stream>>>(dw2_w, dw2_b, bn2_g, bn2_b, bn2_m, bn2_v,
                                         dwt, dsc, dsh);
    lpu_kernel<<<nblk1, 256, 0, stream>>>(x, lpu_w, lpu_b, x1, part1);
    lnreduce_kernel<<<B_, 256, 0, stream>>>(part1, nblk1 / B_, stats);
    kvconv_kernel<<<(int)((nkv + 255) / 256), 256, 0, stream>>>(x1, dw_w, dw_b, kvb);
    tln_kernel<<<dim3(25, 8, B_), 256, 0, stream>>>(x1, stats, x1n);
    // q/k/v projections
    mfma_gemm<0><<<dim3(7, 2, B_), 256, 0, stream>>>(
        x1n, wbf, NPIX, 256, 256, bq, nullptr, nullptr, nullptr, nullptr,
        nullptr, nullptr, qb, nullptr);
    mfma_gemm<0><<<dim3(2, 2, B_), 256, 0, stream>>>(
        kvb, wbf + 65536, NKPIX, 256, 256, bk, nullptr, nullptr, nullptr, nullptr,
        nullptr, nullptr, kb, nullptr);
    mfma_gemm<0><<<dim3(2, 2, B_), 256, 0, stream>>>(
        kvb, wbf + 131072, NKPIX, 256, 256, bv, nullptr, nullptr, nullptr, nullptr,
        nullptr, nullptr, vb, nullptr);
    attn_kernel<<<B_ * 32, 256, 0, stream>>>(qb, kb, vb, posb, tmpb);
    // wo + flat residual + per-wave LN2 partials (grid 7x2x32 -> 56 slots per b)
    mfma_gemm<2><<<dim3(7, 2, B_), 256, 0, stream>>>(
        tmpb, wbf + 196608, NPIX, 256, 256, bo, nullptr, nullptr, nullptr, nullptr,
        x1, part2, nullptr, x2c);
    lnreduce_kernel<<<B_, 256, 0, stream>>>(part2, 56, stats + 64);
    tln_kernel<<<dim3(25, 8, B_), 256, 0, stream>>>(x2c, stats + 64, t1n);
    // conv1 1x1 + BN1 + GELU
    mfma_gemm<1><<<dim3(7, 8, B_), 256, 0, stream>>>(
        t1n, wbf + 262144, NPIX, CM, 256, c1_b, bn1_g, bn1_b, bn1_m, bn1_v,
        nullptr, nullptr, t2, nullptr);
    dwgelu_kernel<<<(int)(B_ * NPIX * 128 / 256), 256, 0, stream>>>(t2, dwt, dsc, dsh, t3);
    // conv2 1x1 + BN3 + residual -> d_out (channel-major)
    mfma_gemm<3><<<dim3(7, 2, B_), 256, 0, stream>>>(
        t3, wbf + 524288, NPIX, 256, CM, c2_b, bn3_g, bn3_b, bn3_m, bn3_v,
        x2c, nullptr, nullptr, outp);
}